// Round 1
// baseline (5770.303 us; speedup 1.0000x reference)
//
#include <hip/hip_runtime.h>

#define N_NODES 100000
#define N_EDGES 3200000
#define N_FEAT  512
#define HID     16
#define N_CLASS 40

// ---------------------------------------------------------------------------
// Stage 1: h = relu(x @ W1^T + b1).   x:[N,512] f32, W1:[16,512].
// One wave per row. W1 staged in LDS (32 KB). Lane l covers cols {4l..4l+3}
// and {256+4l..256+4l+3} -> fully coalesced float4 global loads and
// contiguous-1KB ds_read_b128 (optimal LDS pattern). Butterfly-reduce 16
// accumulators, lane 0 stores 4x float4.
// ---------------------------------------------------------------------------
__global__ __launch_bounds__(256) void k_lin1(const float* __restrict__ x,
                                              const float* __restrict__ w1,
                                              const float* __restrict__ b1,
                                              float* __restrict__ h) {
    __shared__ float w1s[HID][N_FEAT];
    __shared__ float b1s[HID];
    for (int i = threadIdx.x; i < HID * N_FEAT / 4; i += 256)
        ((float4*)&w1s[0][0])[i] = ((const float4*)w1)[i];
    if (threadIdx.x < HID) b1s[threadIdx.x] = b1[threadIdx.x];
    __syncthreads();

    const int wave = threadIdx.x >> 6;
    const int lane = threadIdx.x & 63;
    const int row  = blockIdx.x * 4 + wave;
    if (row >= N_NODES) return;

    const float4* xr = (const float4*)(x + (size_t)row * N_FEAT);
    const float4 xv0 = xr[lane];
    const float4 xv1 = xr[64 + lane];

    float acc[HID];
#pragma unroll
    for (int j = 0; j < HID; j++) {
        const float4 w0 = ((const float4*)&w1s[j][0])[lane];
        const float4 w1v = ((const float4*)&w1s[j][0])[64 + lane];
        acc[j] = xv0.x * w0.x + xv0.y * w0.y + xv0.z * w0.z + xv0.w * w0.w
               + xv1.x * w1v.x + xv1.y * w1v.y + xv1.z * w1v.z + xv1.w * w1v.w;
    }
#pragma unroll
    for (int j = 0; j < HID; j++) {
        float v = acc[j];
#pragma unroll
        for (int off = 32; off > 0; off >>= 1) v += __shfl_xor(v, off);
        acc[j] = v;
    }
    if (lane == 0) {
        float4* hr = (float4*)(h + (size_t)row * HID);
#pragma unroll
        for (int q = 0; q < 4; q++) {
            float4 o;
            o.x = fmaxf(acc[q * 4 + 0] + b1s[q * 4 + 0], 0.f);
            o.y = fmaxf(acc[q * 4 + 1] + b1s[q * 4 + 1], 0.f);
            o.z = fmaxf(acc[q * 4 + 2] + b1s[q * 4 + 2], 0.f);
            o.w = fmaxf(acc[q * 4 + 3] + b1s[q * 4 + 3], 0.f);
            hr[q] = o;
        }
    }
}

// ---------------------------------------------------------------------------
// Per-node: xn = h/max(||h||,1e-12); zero s and hout (accumulators).
// ---------------------------------------------------------------------------
__global__ __launch_bounds__(256) void k_norm(const float* __restrict__ h,
                                              float* __restrict__ xn,
                                              float* __restrict__ s,
                                              float* __restrict__ hout) {
    const int n = blockIdx.x * 256 + threadIdx.x;
    if (n >= N_NODES) return;
    const float4* hr = (const float4*)(h + (size_t)n * HID);
    float4 a = hr[0], b = hr[1], c = hr[2], d = hr[3];
    float ss = a.x*a.x + a.y*a.y + a.z*a.z + a.w*a.w
             + b.x*b.x + b.y*b.y + b.z*b.z + b.w*b.w
             + c.x*c.x + c.y*c.y + c.z*c.z + c.w*c.w
             + d.x*d.x + d.y*d.y + d.z*d.z + d.w*d.w;
    const float rn = 1.f / fmaxf(sqrtf(ss), 1e-12f);
    float4* xr = (float4*)(xn + (size_t)n * HID);
    a.x*=rn; a.y*=rn; a.z*=rn; a.w*=rn;
    b.x*=rn; b.y*=rn; b.z*=rn; b.w*=rn;
    c.x*=rn; c.y*=rn; c.z*=rn; c.w*=rn;
    d.x*=rn; d.y*=rn; d.z*=rn; d.w*=rn;
    xr[0]=a; xr[1]=b; xr[2]=c; xr[3]=d;
    s[n] = 0.f;
    float4 z = make_float4(0.f,0.f,0.f,0.f);
    float4* ho = (float4*)(hout + (size_t)n * HID);
    ho[0]=z; ho[1]=z; ho[2]=z; ho[3]=z;
}

// ---------------------------------------------------------------------------
// Edge pass 1: e = exp(beta*dot(xn[dst],xn[src]) - |beta|); s[dst] += e.
// Softmax shift uses the constant bound |beta| instead of segment_max
// (shift-invariant; alpha in [-|beta|,|beta|] so exp in [e^-2, 1]).
// ---------------------------------------------------------------------------
__global__ __launch_bounds__(256) void k_edge1(const int* __restrict__ src,
                                               const int* __restrict__ dst,
                                               const float* __restrict__ xn,
                                               const float* __restrict__ betap,
                                               float* __restrict__ ev,
                                               float* __restrict__ s) {
    const int e = blockIdx.x * 256 + threadIdx.x;
    if (e >= N_EDGES) return;
    const float beta = betap ? betap[0] : 1.0f;
    const int si = src[e], di = dst[e];
    const float4* A = (const float4*)(xn + (size_t)si * HID);
    const float4* B = (const float4*)(xn + (size_t)di * HID);
    float4 a0=A[0], a1=A[1], a2=A[2], a3=A[3];
    float4 b0=B[0], b1=B[1], b2=B[2], b3=B[3];
    float d = a0.x*b0.x + a0.y*b0.y + a0.z*b0.z + a0.w*b0.w
            + a1.x*b1.x + a1.y*b1.y + a1.z*b1.z + a1.w*b1.w
            + a2.x*b2.x + a2.y*b2.y + a2.z*b2.z + a2.w*b2.w
            + a3.x*b3.x + a3.y*b3.y + a3.z*b3.z + a3.w*b3.w;
    const float val = __expf(beta * d - fabsf(beta));
    ev[e] = val;
    unsafeAtomicAdd(&s[di], val);
}

// ---------------------------------------------------------------------------
// Edge pass 2: w = e/max(s[dst],1e-16); out[dst] += w * h[src]  (16 floats).
// ---------------------------------------------------------------------------
__global__ __launch_bounds__(256) void k_edge2(const int* __restrict__ src,
                                               const int* __restrict__ dst,
                                               const float* __restrict__ ev,
                                               const float* __restrict__ s,
                                               const float* __restrict__ h,
                                               float* __restrict__ out) {
    const int e = blockIdx.x * 256 + threadIdx.x;
    if (e >= N_EDGES) return;
    const int si = src[e], di = dst[e];
    const float w = ev[e] / fmaxf(s[di], 1e-16f);
    const float4* hr = (const float4*)(h + (size_t)si * HID);
    float* orow = out + (size_t)di * HID;
#pragma unroll
    for (int q = 0; q < 4; q++) {
        const float4 hv = hr[q];
        unsafeAtomicAdd(orow + q * 4 + 0, w * hv.x);
        unsafeAtomicAdd(orow + q * 4 + 1, w * hv.y);
        unsafeAtomicAdd(orow + q * 4 + 2, w * hv.z);
        unsafeAtomicAdd(orow + q * 4 + 3, w * hv.w);
    }
}

// ---------------------------------------------------------------------------
// Stage 3: logits = h @ W2^T + b2; out = log_softmax(logits). Thread/node.
// W2 (40x16) in LDS, read uniformly (broadcast).
// ---------------------------------------------------------------------------
__global__ __launch_bounds__(256) void k_lin2(const float* __restrict__ h,
                                              const float* __restrict__ w2,
                                              const float* __restrict__ b2,
                                              float* __restrict__ out) {
    __shared__ float w2s[N_CLASS][HID];
    __shared__ float b2s[N_CLASS];
    for (int i = threadIdx.x; i < N_CLASS * HID; i += 256)
        ((float*)w2s)[i] = w2[i];
    if (threadIdx.x < N_CLASS) b2s[threadIdx.x] = b2[threadIdx.x];
    __syncthreads();

    const int n = blockIdx.x * 256 + threadIdx.x;
    if (n >= N_NODES) return;

    float hv[HID];
    const float4* hr = (const float4*)(h + (size_t)n * HID);
#pragma unroll
    for (int q = 0; q < 4; q++) {
        const float4 v = hr[q];
        hv[q*4+0]=v.x; hv[q*4+1]=v.y; hv[q*4+2]=v.z; hv[q*4+3]=v.w;
    }

    float lg[N_CLASS];
    float m = -3.0e38f;
#pragma unroll
    for (int j = 0; j < N_CLASS; j++) {
        float acc = b2s[j];
#pragma unroll
        for (int k = 0; k < HID; k++) acc += hv[k] * w2s[j][k];
        lg[j] = acc;
        m = fmaxf(m, acc);
    }
    float sum = 0.f;
#pragma unroll
    for (int j = 0; j < N_CLASS; j++) sum += __expf(lg[j] - m);
    const float lse = m + __logf(sum);

    float4* orow = (float4*)(out + (size_t)n * N_CLASS);
#pragma unroll
    for (int q = 0; q < N_CLASS / 4; q++) {
        float4 o;
        o.x = lg[q*4+0] - lse;
        o.y = lg[q*4+1] - lse;
        o.z = lg[q*4+2] - lse;
        o.w = lg[q*4+3] - lse;
        orow[q] = o;
    }
}

extern "C" void kernel_launch(void* const* d_in, const int* in_sizes, int n_in,
                              void* d_out, int out_size, void* d_ws, size_t ws_size,
                              hipStream_t stream) {
    const float* x     = (const float*)d_in[0];
    const int*   ei    = (const int*)  d_in[1];   // [2][E]: row0=src, row1=dst
    const float* w1    = (const float*)d_in[2];
    const float* b1    = (const float*)d_in[3];
    const float* beta2 = (const float*)d_in[4];
    const float* w2    = (const float*)d_in[5];
    const float* b2    = (const float*)d_in[6];
    float* out = (float*)d_out;

    float* ws   = (float*)d_ws;
    float* hA   = ws;                       // [N,16]
    float* hB   = hA + (size_t)N_NODES * HID;
    float* xn   = hB + (size_t)N_NODES * HID;
    float* sden = xn + (size_t)N_NODES * HID;
    float* ev   = sden + N_NODES;           // [E]

    const int* srcp = ei;
    const int* dstp = ei + N_EDGES;

    const int nodeGrid = (N_NODES + 255) / 256;
    const int rowGrid  = N_NODES / 4;        // 25000, wave per row
    const int edgeGrid = N_EDGES / 256;      // 12500

    k_lin1<<<rowGrid, 256, 0, stream>>>(x, w1, b1, hA);

    // AGNN layer 1 (beta = 1.0 fixed)
    k_norm <<<nodeGrid, 256, 0, stream>>>(hA, xn, sden, hB);
    k_edge1<<<edgeGrid, 256, 0, stream>>>(srcp, dstp, xn, nullptr, ev, sden);
    k_edge2<<<edgeGrid, 256, 0, stream>>>(srcp, dstp, ev, sden, hA, hB);

    // AGNN layer 2 (beta = beta2[0] from device)
    k_norm <<<nodeGrid, 256, 0, stream>>>(hB, xn, sden, hA);
    k_edge1<<<edgeGrid, 256, 0, stream>>>(srcp, dstp, xn, beta2, ev, sden);
    k_edge2<<<edgeGrid, 256, 0, stream>>>(srcp, dstp, ev, sden, hB, hA);

    k_lin2<<<nodeGrid, 256, 0, stream>>>(hA, w2, b2, out);
}

// Round 2
// 759.127 us; speedup vs baseline: 7.6012x; 7.6012x over previous
//
#include <hip/hip_runtime.h>

#define N_NODES 100000
#define N_EDGES 3200000
#define N_FEAT  512
#define HID     16
#define N_CLASS 40

// ============================== Stage 1 =====================================
// h = relu(x @ W1^T + b1).  One wave per row; W1 (32 KB) in LDS.
__global__ __launch_bounds__(256) void k_lin1(const float* __restrict__ x,
                                              const float* __restrict__ w1,
                                              const float* __restrict__ b1,
                                              float* __restrict__ h) {
    __shared__ float w1s[HID][N_FEAT];
    __shared__ float b1s[HID];
    for (int i = threadIdx.x; i < HID * N_FEAT / 4; i += 256)
        ((float4*)&w1s[0][0])[i] = ((const float4*)w1)[i];
    if (threadIdx.x < HID) b1s[threadIdx.x] = b1[threadIdx.x];
    __syncthreads();

    const int wave = threadIdx.x >> 6;
    const int lane = threadIdx.x & 63;
    const int row  = blockIdx.x * 4 + wave;
    if (row >= N_NODES) return;

    const float4* xr = (const float4*)(x + (size_t)row * N_FEAT);
    const float4 xv0 = xr[lane];
    const float4 xv1 = xr[64 + lane];

    float acc[HID];
#pragma unroll
    for (int j = 0; j < HID; j++) {
        const float4 w0 = ((const float4*)&w1s[j][0])[lane];
        const float4 w1v = ((const float4*)&w1s[j][0])[64 + lane];
        acc[j] = xv0.x * w0.x + xv0.y * w0.y + xv0.z * w0.z + xv0.w * w0.w
               + xv1.x * w1v.x + xv1.y * w1v.y + xv1.z * w1v.z + xv1.w * w1v.w;
    }
#pragma unroll
    for (int j = 0; j < HID; j++) {
        float v = acc[j];
#pragma unroll
        for (int off = 32; off > 0; off >>= 1) v += __shfl_xor(v, off);
        acc[j] = v;
    }
    if (lane == 0) {
        float4* hr = (float4*)(h + (size_t)row * HID);
#pragma unroll
        for (int q = 0; q < 4; q++) {
            float4 o;
            o.x = fmaxf(acc[q * 4 + 0] + b1s[q * 4 + 0], 0.f);
            o.y = fmaxf(acc[q * 4 + 1] + b1s[q * 4 + 1], 0.f);
            o.z = fmaxf(acc[q * 4 + 2] + b1s[q * 4 + 2], 0.f);
            o.w = fmaxf(acc[q * 4 + 3] + b1s[q * 4 + 3], 0.f);
            hr[q] = o;
        }
    }
}

// ============================== CSR build ===================================
__global__ __launch_bounds__(256) void k_zero(int* __restrict__ p, int n) {
    const int i = blockIdx.x * 256 + threadIdx.x;
    if (i < n) p[i] = 0;
}

__global__ __launch_bounds__(256) void k_hist(const int* __restrict__ dst,
                                              int* __restrict__ counts) {
    const int e = blockIdx.x * 256 + threadIdx.x;
    if (e < N_EDGES) atomicAdd(&counts[dst[e]], 1);
}

// block sums over 1024-element chunks
__global__ __launch_bounds__(256) void k_scan1(const int* __restrict__ counts,
                                               int* __restrict__ blksum) {
    __shared__ int red[256];
    const int t = threadIdx.x;
    const int base = blockIdx.x * 1024 + t * 4;
    int s = 0;
#pragma unroll
    for (int q = 0; q < 4; q++) {
        const int i = base + q;
        if (i < N_NODES) s += counts[i];
    }
    red[t] = s; __syncthreads();
    for (int o = 128; o > 0; o >>= 1) {
        if (t < o) red[t] += red[t + o];
        __syncthreads();
    }
    if (t == 0) blksum[blockIdx.x] = red[0];
}

// single-block exclusive scan of block sums (nb <= 128)
__global__ __launch_bounds__(128) void k_scan2(const int* __restrict__ blksum,
                                               int* __restrict__ blkoff, int nb) {
    __shared__ int buf[128];
    const int t = threadIdx.x;
    const int v = (t < nb) ? blksum[t] : 0;
    buf[t] = v; __syncthreads();
    for (int o = 1; o < 128; o <<= 1) {
        const int add = (t >= o) ? buf[t - o] : 0;
        __syncthreads();
        buf[t] += add;
        __syncthreads();
    }
    if (t < nb) blkoff[t] = buf[t] - v;   // exclusive
}

// local exclusive scan + global offset -> row_start (and cursor copy)
__global__ __launch_bounds__(256) void k_scan3(const int* __restrict__ counts,
                                               const int* __restrict__ blkoff,
                                               int* __restrict__ row_start,
                                               int* __restrict__ cursor) {
    __shared__ int sc[256];
    const int t = threadIdx.x;
    const int base = blockIdx.x * 1024 + t * 4;
    int c[4]; int s = 0;
#pragma unroll
    for (int q = 0; q < 4; q++) {
        const int i = base + q;
        c[q] = (i < N_NODES) ? counts[i] : 0;
        s += c[q];
    }
    sc[t] = s; __syncthreads();
    const int own = s;
    for (int o = 1; o < 256; o <<= 1) {
        const int add = (t >= o) ? sc[t - o] : 0;
        __syncthreads();
        sc[t] += add;
        __syncthreads();
    }
    int ex = sc[t] - own + blkoff[blockIdx.x];
#pragma unroll
    for (int q = 0; q < 4; q++) {
        const int i = base + q;
        if (i < N_NODES) { row_start[i] = ex; cursor[i] = ex; }
        ex += c[q];
    }
    if (blockIdx.x == 0 && t == 0) row_start[N_NODES] = N_EDGES;
}

__global__ __launch_bounds__(256) void k_scatter(const int* __restrict__ src,
                                                 const int* __restrict__ dst,
                                                 int* __restrict__ cursor,
                                                 int* __restrict__ csr_src) {
    const int e = blockIdx.x * 256 + threadIdx.x;
    if (e >= N_EDGES) return;
    const int d = dst[e];
    const int p = atomicAdd(&cursor[d], 1);
    csr_src[p] = src[e];
}

// ============================== Per-node norm ===============================
__global__ __launch_bounds__(256) void k_norm(const float* __restrict__ h,
                                              float* __restrict__ xn) {
    const int n = blockIdx.x * 256 + threadIdx.x;
    if (n >= N_NODES) return;
    const float4* hr = (const float4*)(h + (size_t)n * HID);
    float4 a = hr[0], b = hr[1], c = hr[2], d = hr[3];
    float ss = a.x*a.x + a.y*a.y + a.z*a.z + a.w*a.w
             + b.x*b.x + b.y*b.y + b.z*b.z + b.w*b.w
             + c.x*c.x + c.y*c.y + c.z*c.z + c.w*c.w
             + d.x*d.x + d.y*d.y + d.z*d.z + d.w*d.w;
    const float rn = 1.f / fmaxf(sqrtf(ss), 1e-12f);
    float4* xr = (float4*)(xn + (size_t)n * HID);
    a.x*=rn; a.y*=rn; a.z*=rn; a.w*=rn;
    b.x*=rn; b.y*=rn; b.z*=rn; b.w*=rn;
    c.x*=rn; c.y*=rn; c.z*=rn; c.w*=rn;
    d.x*=rn; d.y*=rn; d.z*=rn; d.w*=rn;
    xr[0]=a; xr[1]=b; xr[2]=c; xr[3]=d;
}

// ============================== Fused AGNN gather ===========================
// 16 lanes per dst node. Lane l owns feature l. For each 16-edge batch, lane l
// computes edge (t+l)'s cosine logit + weight; weights/src broadcast via
// __shfl(.,j,16); every lane accumulates its feature with a coalesced 64 B
// row read of h[sj]. No atomics anywhere.
__global__ __launch_bounds__(256) void k_agnn(const int* __restrict__ row_start,
                                              const int* __restrict__ csr_src,
                                              const float* __restrict__ xn,
                                              const float* __restrict__ h,
                                              const float* __restrict__ betap,
                                              float* __restrict__ out) {
    const int l    = threadIdx.x & 15;
    const int node = (blockIdx.x * 256 + threadIdx.x) >> 4;   // grid exact
    const float beta  = betap ? betap[0] : 1.0f;
    const float shift = fabsf(beta);

    const int rs = row_start[node];
    const int re = row_start[node + 1];

    const float4* xd = (const float4*)(xn + (size_t)node * HID);
    const float4 d0 = xd[0], d1 = xd[1], d2 = xd[2], d3 = xd[3];

    float acc = 0.f, sw = 0.f;
    for (int t = rs; t < re; t += 16) {
        const int k = t + l;
        const bool ok = (k < re);
        const int sidx = ok ? csr_src[k] : 0;
        const float4* xs = (const float4*)(xn + (size_t)sidx * HID);
        const float4 a0 = xs[0], a1 = xs[1], a2 = xs[2], a3 = xs[3];
        const float dot =
              a0.x*d0.x + a0.y*d0.y + a0.z*d0.z + a0.w*d0.w
            + a1.x*d1.x + a1.y*d1.y + a1.z*d1.z + a1.w*d1.w
            + a2.x*d2.x + a2.y*d2.y + a2.z*d2.z + a2.w*d2.w
            + a3.x*d3.x + a3.y*d3.y + a3.z*d3.z + a3.w*d3.w;
        const float w = ok ? __expf(beta * dot - shift) : 0.f;
#pragma unroll
        for (int j = 0; j < 16; j++) {
            const float wj = __shfl(w, j, 16);
            const int   sj = __shfl(sidx, j, 16);
            sw  += wj;
            acc += wj * h[(size_t)sj * HID + l];
        }
    }
    out[(size_t)node * HID + l] = acc / fmaxf(sw, 1e-16f);
}

// ============================== Stage 3 =====================================
__global__ __launch_bounds__(256) void k_lin2(const float* __restrict__ h,
                                              const float* __restrict__ w2,
                                              const float* __restrict__ b2,
                                              float* __restrict__ out) {
    __shared__ float w2s[N_CLASS][HID];
    __shared__ float b2s[N_CLASS];
    for (int i = threadIdx.x; i < N_CLASS * HID; i += 256)
        ((float*)w2s)[i] = w2[i];
    if (threadIdx.x < N_CLASS) b2s[threadIdx.x] = b2[threadIdx.x];
    __syncthreads();

    const int n = blockIdx.x * 256 + threadIdx.x;
    if (n >= N_NODES) return;

    float hv[HID];
    const float4* hr = (const float4*)(h + (size_t)n * HID);
#pragma unroll
    for (int q = 0; q < 4; q++) {
        const float4 v = hr[q];
        hv[q*4+0]=v.x; hv[q*4+1]=v.y; hv[q*4+2]=v.z; hv[q*4+3]=v.w;
    }

    float lg[N_CLASS];
    float m = -3.0e38f;
#pragma unroll
    for (int j = 0; j < N_CLASS; j++) {
        float acc = b2s[j];
#pragma unroll
        for (int k = 0; k < HID; k++) acc += hv[k] * w2s[j][k];
        lg[j] = acc;
        m = fmaxf(m, acc);
    }
    float sum = 0.f;
#pragma unroll
    for (int j = 0; j < N_CLASS; j++) sum += __expf(lg[j] - m);
    const float lse = m + __logf(sum);

    float4* orow = (float4*)(out + (size_t)n * N_CLASS);
#pragma unroll
    for (int q = 0; q < N_CLASS / 4; q++) {
        float4 o;
        o.x = lg[q*4+0] - lse;
        o.y = lg[q*4+1] - lse;
        o.z = lg[q*4+2] - lse;
        o.w = lg[q*4+3] - lse;
        orow[q] = o;
    }
}

// ============================== Launch ======================================
extern "C" void kernel_launch(void* const* d_in, const int* in_sizes, int n_in,
                              void* d_out, int out_size, void* d_ws, size_t ws_size,
                              hipStream_t stream) {
    const float* x     = (const float*)d_in[0];
    const int*   ei    = (const int*)  d_in[1];   // [2][E]: row0=src, row1=dst
    const float* w1    = (const float*)d_in[2];
    const float* b1    = (const float*)d_in[3];
    const float* beta2 = (const float*)d_in[4];
    const float* w2    = (const float*)d_in[5];
    const float* b2    = (const float*)d_in[6];
    float* out = (float*)d_out;

    const int* srcp = ei;
    const int* dstp = ei + N_EDGES;

    // workspace layout
    float* hA = (float*)d_ws;                          // [N,16]
    float* hB = hA + (size_t)N_NODES * HID;            // [N,16]
    float* xn = hB + (size_t)N_NODES * HID;            // [N,16]
    int* counts    = (int*)(xn + (size_t)N_NODES * HID);
    int* row_start = counts + N_NODES;                 // [N+1]
    int* cursor    = row_start + N_NODES + 1;          // [N]
    int* blk       = cursor + N_NODES;                 // [128] scan temps
    int* blkoff    = blk + 128;                        // [128]
    int* csr_src   = blkoff + 128;                     // [E]

    const int nodeGrid = (N_NODES + 255) / 256;        // 391
    const int edgeGrid = N_EDGES / 256;                // 12500
    const int scanGrid = (N_NODES + 1023) / 1024;      // 98
    const int rowGrid  = N_NODES / 4;                  // 25000
    const int agnnGrid = N_NODES * HID / 256;          // 6250

    // ---- CSR build (per call; graph is constant but no caching allowed) ----
    k_zero   <<<nodeGrid, 256, 0, stream>>>(counts, N_NODES);
    k_hist   <<<edgeGrid, 256, 0, stream>>>(dstp, counts);
    k_scan1  <<<scanGrid, 256, 0, stream>>>(counts, blk);
    k_scan2  <<<1,        128, 0, stream>>>(blk, blkoff, scanGrid);
    k_scan3  <<<scanGrid, 256, 0, stream>>>(counts, blkoff, row_start, cursor);
    k_scatter<<<edgeGrid, 256, 0, stream>>>(srcp, dstp, cursor, csr_src);

    // ---- network ----
    k_lin1<<<rowGrid, 256, 0, stream>>>(x, w1, b1, hA);

    k_norm<<<nodeGrid, 256, 0, stream>>>(hA, xn);
    k_agnn<<<agnnGrid, 256, 0, stream>>>(row_start, csr_src, xn, hA, nullptr, hB);

    k_norm<<<nodeGrid, 256, 0, stream>>>(hB, xn);
    k_agnn<<<agnnGrid, 256, 0, stream>>>(row_start, csr_src, xn, hB, beta2, hA);

    k_lin2<<<nodeGrid, 256, 0, stream>>>(hA, w2, b2, out);
}

// Round 3
// 427.674 us; speedup vs baseline: 13.4923x; 1.7750x over previous
//
#include <hip/hip_runtime.h>

#define N_NODES 100000
#define N_EDGES 3200000
#define N_FEAT  512
#define HID     16
#define N_CLASS 40

#define BSHIFT  9                      // 512 nodes per bucket
#define BMASK   ((1 << BSHIFT) - 1)
#define NB      196                    // ceil(100000 / 512)
#define CAP     18432                  // max edges/bucket (mean 16384, +16 sigma)
#define EPB     4096                   // edges per binning block

// ============================== Stage 1 =====================================
// h = relu(x @ W1^T + b1).  One wave per row; W1 (32 KB) in LDS.
__global__ __launch_bounds__(256) void k_lin1(const float* __restrict__ x,
                                              const float* __restrict__ w1,
                                              const float* __restrict__ b1,
                                              float* __restrict__ h) {
    __shared__ float w1s[HID][N_FEAT];
    __shared__ float b1s[HID];
    for (int i = threadIdx.x; i < HID * N_FEAT / 4; i += 256)
        ((float4*)&w1s[0][0])[i] = ((const float4*)w1)[i];
    if (threadIdx.x < HID) b1s[threadIdx.x] = b1[threadIdx.x];
    __syncthreads();

    const int wave = threadIdx.x >> 6;
    const int lane = threadIdx.x & 63;
    const int row  = blockIdx.x * 4 + wave;
    if (row >= N_NODES) return;

    const float4* xr = (const float4*)(x + (size_t)row * N_FEAT);
    const float4 xv0 = xr[lane];
    const float4 xv1 = xr[64 + lane];

    float acc[HID];
#pragma unroll
    for (int j = 0; j < HID; j++) {
        const float4 w0 = ((const float4*)&w1s[j][0])[lane];
        const float4 w1v = ((const float4*)&w1s[j][0])[64 + lane];
        acc[j] = xv0.x * w0.x + xv0.y * w0.y + xv0.z * w0.z + xv0.w * w0.w
               + xv1.x * w1v.x + xv1.y * w1v.y + xv1.z * w1v.z + xv1.w * w1v.w;
    }
#pragma unroll
    for (int j = 0; j < HID; j++) {
        float v = acc[j];
#pragma unroll
        for (int off = 32; off > 0; off >>= 1) v += __shfl_xor(v, off);
        acc[j] = v;
    }
    if (lane == 0) {
        float4* hr = (float4*)(h + (size_t)row * HID);
#pragma unroll
        for (int q = 0; q < 4; q++) {
            float4 o;
            o.x = fmaxf(acc[q * 4 + 0] + b1s[q * 4 + 0], 0.f);
            o.y = fmaxf(acc[q * 4 + 1] + b1s[q * 4 + 1], 0.f);
            o.z = fmaxf(acc[q * 4 + 2] + b1s[q * 4 + 2], 0.f);
            o.w = fmaxf(acc[q * 4 + 3] + b1s[q * 4 + 3], 0.f);
            hr[q] = o;
        }
    }
}

// ============================== CSR build (binned) ==========================
__global__ __launch_bounds__(256) void k_zero(int* __restrict__ p, int n) {
    const int i = blockIdx.x * 256 + threadIdx.x;
    if (i < n) p[i] = 0;
}

// per-block LDS histogram of dst-buckets -> few global atomics
__global__ __launch_bounds__(256) void k_bhist(const int* __restrict__ dst,
                                               int* __restrict__ gcount) {
    __shared__ int h[NB];
    const int t = threadIdx.x;
    for (int i = t; i < NB; i += 256) h[i] = 0;
    __syncthreads();
    const int e0 = blockIdx.x * EPB;
#pragma unroll
    for (int k = 0; k < EPB / 256; k++) {
        const int e = e0 + k * 256 + t;
        if (e < N_EDGES) atomicAdd(&h[dst[e] >> BSHIFT], 1);
    }
    __syncthreads();
    for (int i = t; i < NB; i += 256)
        if (h[i]) atomicAdd(&gcount[i], h[i]);
}

// exclusive scan of 196 bucket counts -> bstart[NB+1] and write cursors
__global__ __launch_bounds__(256) void k_bscan(const int* __restrict__ gcount,
                                               int* __restrict__ bstart,
                                               int* __restrict__ cursor) {
    __shared__ int buf[256];
    const int t = threadIdx.x;
    const int v = (t < NB) ? gcount[t] : 0;
    buf[t] = v; __syncthreads();
    for (int o = 1; o < 256; o <<= 1) {
        const int a = (t >= o) ? buf[t - o] : 0;
        __syncthreads();
        buf[t] += a;
        __syncthreads();
    }
    if (t < NB) { const int ex = buf[t] - v; bstart[t] = ex; cursor[t] = ex; }
    if (t == 0) bstart[NB] = N_EDGES;
}

// group EPB edges by bucket in LDS, reserve contiguous chunks, flush coalesced.
// binned[] entry = (src << 9) | (dst & 511), grouped by bucket.
__global__ __launch_bounds__(256) void k_bin(const int* __restrict__ src,
                                             const int* __restrict__ dst,
                                             int* __restrict__ cursor,
                                             int* __restrict__ binned) {
    __shared__ int hist[NB];
    __shared__ int lofs[NB];
    __shared__ int base[NB];
    __shared__ int rk[NB];
    __shared__ int buf[256];
    __shared__ int stage[EPB];
    __shared__ unsigned short sbkt[EPB];

    const int t = threadIdx.x;
    for (int i = t; i < NB; i += 256) { hist[i] = 0; rk[i] = 0; }
    __syncthreads();

    const int e0 = blockIdx.x * EPB;
    int bk[EPB / 256];
    int vv[EPB / 256];
#pragma unroll
    for (int k = 0; k < EPB / 256; k++) {
        const int e = e0 + k * 256 + t;
        if (e < N_EDGES) {
            const int d = dst[e], s = src[e];
            bk[k] = d >> BSHIFT;
            vv[k] = (s << BSHIFT) | (d & BMASK);
            atomicAdd(&hist[bk[k]], 1);
        } else bk[k] = -1;
    }
    __syncthreads();

    // exclusive scan hist -> lofs
    {
        const int v = (t < NB) ? hist[t] : 0;
        buf[t] = v; __syncthreads();
        for (int o = 1; o < 256; o <<= 1) {
            const int a = (t >= o) ? buf[t - o] : 0;
            __syncthreads();
            buf[t] += a;
            __syncthreads();
        }
        if (t < NB) lofs[t] = buf[t] - v;
    }
    // reserve global chunk per bucket
    if (t < NB && hist[t] > 0) base[t] = atomicAdd(&cursor[t], hist[t]);

    // local scatter into stage (grouped by bucket)
#pragma unroll
    for (int k = 0; k < EPB / 256; k++) {
        if (bk[k] >= 0) {
            const int r = atomicAdd(&rk[bk[k]], 1);
            const int slot = lofs[bk[k]] + r;
            stage[slot] = vv[k];
            sbkt[slot] = (unsigned short)bk[k];
        }
    }
    __syncthreads();

    // flush: consecutive slots of a bucket -> consecutive global addresses
    const int nloc = min(EPB, N_EDGES - e0);
    for (int s2 = t; s2 < nloc; s2 += 256) {
        const int b = sbkt[s2];
        binned[base[b] + (s2 - lofs[b])] = stage[s2];
    }
}

// per bucket: counts per node, scan -> row_start, scatter srcs in LDS,
// write csr coalesced IN-PLACE over binned (per-block range, reads precede writes)
__global__ __launch_bounds__(512) void k_csr(const int* __restrict__ bstart,
                                             int* __restrict__ binned,
                                             int* __restrict__ row_start) {
    __shared__ int cnts[512];
    __shared__ int cur[512];
    __shared__ int buf[512];
    __shared__ int lcsr[CAP];

    const int t = threadIdx.x;
    const int b = blockIdx.x;
    const int s0 = bstart[b], s1 = bstart[b + 1];
    const int n = s1 - s0;

    cnts[t] = 0;
    __syncthreads();
    for (int i = t; i < n; i += 512)
        atomicAdd(&cnts[binned[s0 + i] & BMASK], 1);
    __syncthreads();

    // exclusive scan over 512
    {
        const int v = cnts[t];
        buf[t] = v; __syncthreads();
        for (int o = 1; o < 512; o <<= 1) {
            const int a = (t >= o) ? buf[t - o] : 0;
            __syncthreads();
            buf[t] += a;
            __syncthreads();
        }
        cur[t] = buf[t] - v;   // exclusive prefix
        const int node = (b << BSHIFT) + t;
        if (node < N_NODES) row_start[node] = s0 + cur[t];
        if (b == NB - 1 && t == 0) row_start[N_NODES] = N_EDGES;
    }
    __syncthreads();

    for (int i = t; i < n; i += 512) {
        const int v = binned[s0 + i];
        const int p = atomicAdd(&cur[v & BMASK], 1);
        lcsr[p] = v >> BSHIFT;
    }
    __syncthreads();

    for (int i = t; i < n; i += 512) binned[s0 + i] = lcsr[i];
}

// ============================== Per-node norm ===============================
__global__ __launch_bounds__(256) void k_norm(const float* __restrict__ h,
                                              float* __restrict__ xn) {
    const int n = blockIdx.x * 256 + threadIdx.x;
    if (n >= N_NODES) return;
    const float4* hr = (const float4*)(h + (size_t)n * HID);
    float4 a = hr[0], b = hr[1], c = hr[2], d = hr[3];
    float ss = a.x*a.x + a.y*a.y + a.z*a.z + a.w*a.w
             + b.x*b.x + b.y*b.y + b.z*b.z + b.w*b.w
             + c.x*c.x + c.y*c.y + c.z*c.z + c.w*c.w
             + d.x*d.x + d.y*d.y + d.z*d.z + d.w*d.w;
    const float rn = 1.f / fmaxf(sqrtf(ss), 1e-12f);
    float4* xr = (float4*)(xn + (size_t)n * HID);
    a.x*=rn; a.y*=rn; a.z*=rn; a.w*=rn;
    b.x*=rn; b.y*=rn; b.z*=rn; b.w*=rn;
    c.x*=rn; c.y*=rn; c.z*=rn; c.w*=rn;
    d.x*=rn; d.y*=rn; d.z*=rn; d.w*=rn;
    xr[0]=a; xr[1]=b; xr[2]=c; xr[3]=d;
}

// ============================== Fused AGNN gather ===========================
// 16 lanes per dst node; lane l owns feature l; no atomics.
__global__ __launch_bounds__(256) void k_agnn(const int* __restrict__ row_start,
                                              const int* __restrict__ csr_src,
                                              const float* __restrict__ xn,
                                              const float* __restrict__ h,
                                              const float* __restrict__ betap,
                                              float* __restrict__ out) {
    const int l    = threadIdx.x & 15;
    const int node = (blockIdx.x * 256 + threadIdx.x) >> 4;   // grid exact
    const float beta  = betap ? betap[0] : 1.0f;
    const float shift = fabsf(beta);

    const int rs = row_start[node];
    const int re = row_start[node + 1];

    const float4* xd = (const float4*)(xn + (size_t)node * HID);
    const float4 d0 = xd[0], d1 = xd[1], d2 = xd[2], d3 = xd[3];

    float acc = 0.f, sw = 0.f;
    for (int t = rs; t < re; t += 16) {
        const int k = t + l;
        const bool ok = (k < re);
        const int sidx = ok ? csr_src[k] : 0;
        const float4* xs = (const float4*)(xn + (size_t)sidx * HID);
        const float4 a0 = xs[0], a1 = xs[1], a2 = xs[2], a3 = xs[3];
        const float dot =
              a0.x*d0.x + a0.y*d0.y + a0.z*d0.z + a0.w*d0.w
            + a1.x*d1.x + a1.y*d1.y + a1.z*d1.z + a1.w*d1.w
            + a2.x*d2.x + a2.y*d2.y + a2.z*d2.z + a2.w*d2.w
            + a3.x*d3.x + a3.y*d3.y + a3.z*d3.z + a3.w*d3.w;
        const float w = ok ? __expf(beta * dot - shift) : 0.f;
#pragma unroll
        for (int j = 0; j < 16; j++) {
            const float wj = __shfl(w, j, 16);
            const int   sj = __shfl(sidx, j, 16);
            sw  += wj;
            acc += wj * h[(size_t)sj * HID + l];
        }
    }
    out[(size_t)node * HID + l] = acc / fmaxf(sw, 1e-16f);
}

// ============================== Stage 3 =====================================
__global__ __launch_bounds__(256) void k_lin2(const float* __restrict__ h,
                                              const float* __restrict__ w2,
                                              const float* __restrict__ b2,
                                              float* __restrict__ out) {
    __shared__ float w2s[N_CLASS][HID];
    __shared__ float b2s[N_CLASS];
    for (int i = threadIdx.x; i < N_CLASS * HID; i += 256)
        ((float*)w2s)[i] = w2[i];
    if (threadIdx.x < N_CLASS) b2s[threadIdx.x] = b2[threadIdx.x];
    __syncthreads();

    const int n = blockIdx.x * 256 + threadIdx.x;
    if (n >= N_NODES) return;

    float hv[HID];
    const float4* hr = (const float4*)(h + (size_t)n * HID);
#pragma unroll
    for (int q = 0; q < 4; q++) {
        const float4 v = hr[q];
        hv[q*4+0]=v.x; hv[q*4+1]=v.y; hv[q*4+2]=v.z; hv[q*4+3]=v.w;
    }

    float lg[N_CLASS];
    float m = -3.0e38f;
#pragma unroll
    for (int j = 0; j < N_CLASS; j++) {
        float acc = b2s[j];
#pragma unroll
        for (int k = 0; k < HID; k++) acc += hv[k] * w2s[j][k];
        lg[j] = acc;
        m = fmaxf(m, acc);
    }
    float sum = 0.f;
#pragma unroll
    for (int j = 0; j < N_CLASS; j++) sum += __expf(lg[j] - m);
    const float lse = m + __logf(sum);

    float4* orow = (float4*)(out + (size_t)n * N_CLASS);
#pragma unroll
    for (int q = 0; q < N_CLASS / 4; q++) {
        float4 o;
        o.x = lg[q*4+0] - lse;
        o.y = lg[q*4+1] - lse;
        o.z = lg[q*4+2] - lse;
        o.w = lg[q*4+3] - lse;
        orow[q] = o;
    }
}

// ============================== Launch ======================================
extern "C" void kernel_launch(void* const* d_in, const int* in_sizes, int n_in,
                              void* d_out, int out_size, void* d_ws, size_t ws_size,
                              hipStream_t stream) {
    const float* x     = (const float*)d_in[0];
    const int*   ei    = (const int*)  d_in[1];   // [2][E]: row0=src, row1=dst
    const float* w1    = (const float*)d_in[2];
    const float* b1    = (const float*)d_in[3];
    const float* beta2 = (const float*)d_in[4];
    const float* w2    = (const float*)d_in[5];
    const float* b2    = (const float*)d_in[6];
    float* out = (float*)d_out;

    const int* srcp = ei;
    const int* dstp = ei + N_EDGES;

    // workspace layout
    float* hA = (float*)d_ws;                          // [N,16]
    float* hB = hA + (size_t)N_NODES * HID;            // [N,16]
    float* xn = hB + (size_t)N_NODES * HID;            // [N,16]
    int* row_start = (int*)(xn + (size_t)N_NODES * HID); // [N+1]
    int* gcount    = row_start + N_NODES + 1;          // [NB]
    int* bstart    = gcount + NB;                      // [NB+1]
    int* cursor    = bstart + NB + 1;                  // [NB]
    int* binned    = cursor + NB;                      // [E] packed, then csr_src

    const int nodeGrid = (N_NODES + 255) / 256;        // 391
    const int rowGrid  = N_NODES / 4;                  // 25000
    const int binGrid  = (N_EDGES + EPB - 1) / EPB;    // 782
    const int agnnGrid = N_NODES * HID / 256;          // 6250

    // ---- CSR build: coalesced two-level binning ----
    k_zero <<<1,       256, 0, stream>>>(gcount, NB);
    k_bhist<<<binGrid, 256, 0, stream>>>(dstp, gcount);
    k_bscan<<<1,       256, 0, stream>>>(gcount, bstart, cursor);
    k_bin  <<<binGrid, 256, 0, stream>>>(srcp, dstp, cursor, binned);
    k_csr  <<<NB,      512, 0, stream>>>(bstart, binned, row_start);

    // ---- network ----
    k_lin1<<<rowGrid, 256, 0, stream>>>(x, w1, b1, hA);

    k_norm<<<nodeGrid, 256, 0, stream>>>(hA, xn);
    k_agnn<<<agnnGrid, 256, 0, stream>>>(row_start, binned, xn, hA, nullptr, hB);

    k_norm<<<nodeGrid, 256, 0, stream>>>(hB, xn);
    k_agnn<<<agnnGrid, 256, 0, stream>>>(row_start, binned, xn, hB, beta2, hA);

    k_lin2<<<nodeGrid, 256, 0, stream>>>(hA, w2, b2, out);
}

// Round 5
// 323.485 us; speedup vs baseline: 17.8379x; 1.3221x over previous
//
#include <hip/hip_runtime.h>

#define N_NODES 100000
#define N_EDGES 3200000
#define N_FEAT  512
#define HID     16
#define N_CLASS 40

#define BSHIFT  9                      // 512 nodes per bucket
#define BMASK   ((1 << BSHIFT) - 1)
#define NB      196                    // ceil(100000 / 512)
#define CAP     18432                  // max edges/bucket (mean 16384, +16 sigma)
#define EPB     4096                   // edges per binning block

typedef __attribute__((ext_vector_type(8))) short bf16x8;
typedef __attribute__((ext_vector_type(4))) float f32x4;

// exact split: v == hi_f32 + lo_residual; hi = truncated-top-16 (exact),
// lo = bf16(v - hi) (residual <= 2^-8 |v|, its bf16 trunc err <= 2^-16 |v|)
__device__ inline short2 split_bf(float v) {
    const unsigned u = __float_as_uint(v);
    const short hi = (short)(u >> 16);
    const float hf = __uint_as_float(u & 0xFFFF0000u);
    const short lo = (short)(__float_as_uint(v - hf) >> 16);
    return make_short2(hi, lo);
}

// ============================== Stage 1 (MFMA) ==============================
// h = relu(x @ W1^T + b1) via mfma_f32_16x16x32_bf16 with hi/lo split (f32-
// grade accuracy). One wave per 16-row tile; W1 frags pre-arranged in LDS.
// Per K-tile: 2 ds_read_b128 + 3 MFMA; A loaded as 2 float4/lane + split.
#define NT (N_NODES / 16)              // 6250 tiles
__global__ __launch_bounds__(256) void k_lin1(const float* __restrict__ x,
                                              const float* __restrict__ w1,
                                              const float* __restrict__ b1,
                                              float* __restrict__ h) {
    // B-fragment layout: frag f = (kt, lane): col=lane&15, k=kt*32+(lane>>4)*8
    __shared__ __align__(16) short bfH[16 * 64 * 8];   // 16 KB
    __shared__ __align__(16) short bfL[16 * 64 * 8];   // 16 KB

    const int t = threadIdx.x;
    for (int f = t; f < 16 * 64; f += 256) {
        const int kt  = f >> 6;
        const int ln  = f & 63;
        const int col = ln & 15;
        const int k0  = kt * 32 + (ln >> 4) * 8;
        const float4 v0 = *(const float4*)(w1 + col * N_FEAT + k0);
        const float4 v1 = *(const float4*)(w1 + col * N_FEAT + k0 + 4);
        bf16x8 hh, ll;
        short2 r;
        r = split_bf(v0.x); hh[0] = r.x; ll[0] = r.y;
        r = split_bf(v0.y); hh[1] = r.x; ll[1] = r.y;
        r = split_bf(v0.z); hh[2] = r.x; ll[2] = r.y;
        r = split_bf(v0.w); hh[3] = r.x; ll[3] = r.y;
        r = split_bf(v1.x); hh[4] = r.x; ll[4] = r.y;
        r = split_bf(v1.y); hh[5] = r.x; ll[5] = r.y;
        r = split_bf(v1.z); hh[6] = r.x; ll[6] = r.y;
        r = split_bf(v1.w); hh[7] = r.x; ll[7] = r.y;
        ((bf16x8*)bfH)[f] = hh;
        ((bf16x8*)bfL)[f] = ll;
    }
    __syncthreads();

    const int wv   = t >> 6;
    const int l    = t & 63;
    const int tile = blockIdx.x * 4 + wv;
    if (tile >= NT) return;

    const int r0 = tile * 16;
    const float* xp = x + (size_t)(r0 + (l & 15)) * N_FEAT + ((l >> 4) * 8);

    f32x4 acc = {0.f, 0.f, 0.f, 0.f};
    float4 c0 = *(const float4*)(xp);
    float4 c1 = *(const float4*)(xp + 4);
#pragma unroll
    for (int kt = 0; kt < 16; ++kt) {
        float4 n0, n1;
        if (kt < 15) {
            n0 = *(const float4*)(xp + (kt + 1) * 32);
            n1 = *(const float4*)(xp + (kt + 1) * 32 + 4);
        }
        bf16x8 ah, al;
        short2 r;
        r = split_bf(c0.x); ah[0] = r.x; al[0] = r.y;
        r = split_bf(c0.y); ah[1] = r.x; al[1] = r.y;
        r = split_bf(c0.z); ah[2] = r.x; al[2] = r.y;
        r = split_bf(c0.w); ah[3] = r.x; al[3] = r.y;
        r = split_bf(c1.x); ah[4] = r.x; al[4] = r.y;
        r = split_bf(c1.y); ah[5] = r.x; al[5] = r.y;
        r = split_bf(c1.z); ah[6] = r.x; al[6] = r.y;
        r = split_bf(c1.w); ah[7] = r.x; al[7] = r.y;
        const bf16x8 bh = ((const bf16x8*)bfH)[kt * 64 + l];
        const bf16x8 bl = ((const bf16x8*)bfL)[kt * 64 + l];
        acc = __builtin_amdgcn_mfma_f32_16x16x32_bf16(ah, bh, acc, 0, 0, 0);
        acc = __builtin_amdgcn_mfma_f32_16x16x32_bf16(al, bh, acc, 0, 0, 0);
        acc = __builtin_amdgcn_mfma_f32_16x16x32_bf16(ah, bl, acc, 0, 0, 0);
        c0 = n0; c1 = n1;
    }

    // C/D: col = lane&15, row = (lane>>4)*4 + reg   [m89-verified]
    const float bias = b1[l & 15];
#pragma unroll
    for (int r = 0; r < 4; ++r) {
        const int row = r0 + (l >> 4) * 4 + r;
        h[(size_t)row * HID + (l & 15)] = fmaxf(acc[r] + bias, 0.f);
    }
}

// ============================== CSR build (binned) ==========================
__global__ __launch_bounds__(256) void k_zero(int* __restrict__ p, int n) {
    const int i = blockIdx.x * 256 + threadIdx.x;
    if (i < n) p[i] = 0;
}

// per-block LDS histogram of dst-buckets -> few global atomics
__global__ __launch_bounds__(256) void k_bhist(const int* __restrict__ dst,
                                               int* __restrict__ gcount) {
    __shared__ int h[NB];
    const int t = threadIdx.x;
    for (int i = t; i < NB; i += 256) h[i] = 0;
    __syncthreads();
    const int e0 = blockIdx.x * EPB;
#pragma unroll
    for (int k = 0; k < EPB / 256; k++) {
        const int e = e0 + k * 256 + t;
        if (e < N_EDGES) atomicAdd(&h[dst[e] >> BSHIFT], 1);
    }
    __syncthreads();
    for (int i = t; i < NB; i += 256)
        if (h[i]) atomicAdd(&gcount[i], h[i]);
}

// exclusive scan of 196 bucket counts -> bstart[NB+1] and write cursors
__global__ __launch_bounds__(256) void k_bscan(const int* __restrict__ gcount,
                                               int* __restrict__ bstart,
                                               int* __restrict__ cursor) {
    __shared__ int buf[256];
    const int t = threadIdx.x;
    const int v = (t < NB) ? gcount[t] : 0;
    buf[t] = v; __syncthreads();
    for (int o = 1; o < 256; o <<= 1) {
        const int a = (t >= o) ? buf[t - o] : 0;
        __syncthreads();
        buf[t] += a;
        __syncthreads();
    }
    if (t < NB) { const int ex = buf[t] - v; bstart[t] = ex; cursor[t] = ex; }
    if (t == 0) bstart[NB] = N_EDGES;
}

// group EPB edges by bucket in LDS, reserve contiguous chunks, flush coalesced.
// binned[] entry = (src << 9) | (dst & 511), grouped by bucket.
__global__ __launch_bounds__(256) void k_bin(const int* __restrict__ src,
                                             const int* __restrict__ dst,
                                             int* __restrict__ cursor,
                                             int* __restrict__ binned) {
    __shared__ int hist[NB];
    __shared__ int lofs[NB];
    __shared__ int base[NB];
    __shared__ int rk[NB];
    __shared__ int buf[256];
    __shared__ int stage[EPB];
    __shared__ unsigned short sbkt[EPB];

    const int t = threadIdx.x;
    for (int i = t; i < NB; i += 256) { hist[i] = 0; rk[i] = 0; }
    __syncthreads();

    const int e0 = blockIdx.x * EPB;
    int bk[EPB / 256];
    int vv[EPB / 256];
#pragma unroll
    for (int k = 0; k < EPB / 256; k++) {
        const int e = e0 + k * 256 + t;
        if (e < N_EDGES) {
            const int d = dst[e], s = src[e];
            bk[k] = d >> BSHIFT;
            vv[k] = (s << BSHIFT) | (d & BMASK);
            atomicAdd(&hist[bk[k]], 1);
        } else bk[k] = -1;
    }
    __syncthreads();

    // exclusive scan hist -> lofs
    {
        const int v = (t < NB) ? hist[t] : 0;
        buf[t] = v; __syncthreads();
        for (int o = 1; o < 256; o <<= 1) {
            const int a = (t >= o) ? buf[t - o] : 0;
            __syncthreads();
            buf[t] += a;
            __syncthreads();
        }
        if (t < NB) lofs[t] = buf[t] - v;
    }
    // reserve global chunk per bucket
    if (t < NB && hist[t] > 0) base[t] = atomicAdd(&cursor[t], hist[t]);

    // local scatter into stage (grouped by bucket)
#pragma unroll
    for (int k = 0; k < EPB / 256; k++) {
        if (bk[k] >= 0) {
            const int r = atomicAdd(&rk[bk[k]], 1);
            const int slot = lofs[bk[k]] + r;
            stage[slot] = vv[k];
            sbkt[slot] = (unsigned short)bk[k];
        }
    }
    __syncthreads();

    // flush: consecutive slots of a bucket -> consecutive global addresses
    const int nloc = min(EPB, N_EDGES - e0);
    for (int s2 = t; s2 < nloc; s2 += 256) {
        const int b = sbkt[s2];
        binned[base[b] + (s2 - lofs[b])] = stage[s2];
    }
}

// per bucket: counts per node, scan -> row_start, scatter srcs in LDS,
// write csr coalesced IN-PLACE over binned (per-block range, reads precede writes)
__global__ __launch_bounds__(512) void k_csr(const int* __restrict__ bstart,
                                             int* __restrict__ binned,
                                             int* __restrict__ row_start) {
    __shared__ int cnts[512];
    __shared__ int cur[512];
    __shared__ int buf[512];
    __shared__ int lcsr[CAP];

    const int t = threadIdx.x;
    const int b = blockIdx.x;
    const int s0 = bstart[b], s1 = bstart[b + 1];
    const int n = s1 - s0;

    cnts[t] = 0;
    __syncthreads();
    for (int i = t; i < n; i += 512)
        atomicAdd(&cnts[binned[s0 + i] & BMASK], 1);
    __syncthreads();

    // exclusive scan over 512
    {
        const int v = cnts[t];
        buf[t] = v; __syncthreads();
        for (int o = 1; o < 512; o <<= 1) {
            const int a = (t >= o) ? buf[t - o] : 0;
            __syncthreads();
            buf[t] += a;
            __syncthreads();
        }
        cur[t] = buf[t] - v;   // exclusive prefix
        const int node = (b << BSHIFT) + t;
        if (node < N_NODES) row_start[node] = s0 + cur[t];
        if (b == NB - 1 && t == 0) row_start[N_NODES] = N_EDGES;
    }
    __syncthreads();

    for (int i = t; i < n; i += 512) {
        const int v = binned[s0 + i];
        const int p = atomicAdd(&cur[v & BMASK], 1);
        lcsr[p] = v >> BSHIFT;
    }
    __syncthreads();

    for (int i = t; i < n; i += 512) binned[s0 + i] = lcsr[i];
}

// ============================== Per-node norm ===============================
__global__ __launch_bounds__(256) void k_norm(const float* __restrict__ h,
                                              float* __restrict__ xn) {
    const int n = blockIdx.x * 256 + threadIdx.x;
    if (n >= N_NODES) return;
    const float4* hr = (const float4*)(h + (size_t)n * HID);
    float4 a = hr[0], b = hr[1], c = hr[2], d = hr[3];
    float ss = a.x*a.x + a.y*a.y + a.z*a.z + a.w*a.w
             + b.x*b.x + b.y*b.y + b.z*b.z + b.w*b.w
             + c.x*c.x + c.y*c.y + c.z*c.z + c.w*c.w
             + d.x*d.x + d.y*d.y + d.z*d.z + d.w*d.w;
    const float rn = 1.f / fmaxf(sqrtf(ss), 1e-12f);
    float4* xr = (float4*)(xn + (size_t)n * HID);
    a.x*=rn; a.y*=rn; a.z*=rn; a.w*=rn;
    b.x*=rn; b.y*=rn; b.z*=rn; b.w*=rn;
    c.x*=rn; c.y*=rn; c.z*=rn; c.w*=rn;
    d.x*=rn; d.y*=rn; d.z*=rn; d.w*=rn;
    xr[0]=a; xr[1]=b; xr[2]=c; xr[3]=d;
}

// ============================== Fused AGNN gather ===========================
// 16 lanes per dst node; lane l owns feature l; no atomics.
__global__ __launch_bounds__(256) void k_agnn(const int* __restrict__ row_start,
                                              const int* __restrict__ csr_src,
                                              const float* __restrict__ xn,
                                              const float* __restrict__ h,
                                              const float* __restrict__ betap,
                                              float* __restrict__ out) {
    const int l    = threadIdx.x & 15;
    const int node = (blockIdx.x * 256 + threadIdx.x) >> 4;   // grid exact
    const float beta  = betap ? betap[0] : 1.0f;
    const float shift = fabsf(beta);

    const int rs = row_start[node];
    const int re = row_start[node + 1];

    const float4* xd = (const float4*)(xn + (size_t)node * HID);
    const float4 d0 = xd[0], d1 = xd[1], d2 = xd[2], d3 = xd[3];

    float acc = 0.f, sw = 0.f;
    for (int t = rs; t < re; t += 16) {
        const int k = t + l;
        const bool ok = (k < re);
        const int sidx = ok ? csr_src[k] : 0;
        const float4* xs = (const float4*)(xn + (size_t)sidx * HID);
        const float4 a0 = xs[0], a1 = xs[1], a2 = xs[2], a3 = xs[3];
        const float dot =
              a0.x*d0.x + a0.y*d0.y + a0.z*d0.z + a0.w*d0.w
            + a1.x*d1.x + a1.y*d1.y + a1.z*d1.z + a1.w*d1.w
            + a2.x*d2.x + a2.y*d2.y + a2.z*d2.z + a2.w*d2.w
            + a3.x*d3.x + a3.y*d3.y + a3.z*d3.z + a3.w*d3.w;
        const float w = ok ? __expf(beta * dot - shift) : 0.f;
#pragma unroll
        for (int j = 0; j < 16; j++) {
            const float wj = __shfl(w, j, 16);
            const int   sj = __shfl(sidx, j, 16);
            sw  += wj;
            acc += wj * h[(size_t)sj * HID + l];
        }
    }
    out[(size_t)node * HID + l] = acc / fmaxf(sw, 1e-16f);
}

// ============================== Stage 3 =====================================
__global__ __launch_bounds__(256) void k_lin2(const float* __restrict__ h,
                                              const float* __restrict__ w2,
                                              const float* __restrict__ b2,
                                              float* __restrict__ out) {
    __shared__ float w2s[N_CLASS][HID];
    __shared__ float b2s[N_CLASS];
    for (int i = threadIdx.x; i < N_CLASS * HID; i += 256)
        ((float*)w2s)[i] = w2[i];
    if (threadIdx.x < N_CLASS) b2s[threadIdx.x] = b2[threadIdx.x];
    __syncthreads();

    const int n = blockIdx.x * 256 + threadIdx.x;
    if (n >= N_NODES) return;

    float hv[HID];
    const float4* hr = (const float4*)(h + (size_t)n * HID);
#pragma unroll
    for (int q = 0; q < 4; q++) {
        const float4 v = hr[q];
        hv[q*4+0]=v.x; hv[q*4+1]=v.y; hv[q*4+2]=v.z; hv[q*4+3]=v.w;
    }

    float lg[N_CLASS];
    float m = -3.0e38f;
#pragma unroll
    for (int j = 0; j < N_CLASS; j++) {
        float acc = b2s[j];
#pragma unroll
        for (int k = 0; k < HID; k++) acc += hv[k] * w2s[j][k];
        lg[j] = acc;
        m = fmaxf(m, acc);
    }
    float sum = 0.f;
#pragma unroll
    for (int j = 0; j < N_CLASS; j++) sum += __expf(lg[j] - m);
    const float lse = m + __logf(sum);

    float4* orow = (float4*)(out + (size_t)n * N_CLASS);
#pragma unroll
    for (int q = 0; q < N_CLASS / 4; q++) {
        float4 o;
        o.x = lg[q*4+0] - lse;
        o.y = lg[q*4+1] - lse;
        o.z = lg[q*4+2] - lse;
        o.w = lg[q*4+3] - lse;
        orow[q] = o;
    }
}

// ============================== Launch ======================================
extern "C" void kernel_launch(void* const* d_in, const int* in_sizes, int n_in,
                              void* d_out, int out_size, void* d_ws, size_t ws_size,
                              hipStream_t stream) {
    const float* x     = (const float*)d_in[0];
    const int*   ei    = (const int*)  d_in[1];   // [2][E]: row0=src, row1=dst
    const float* w1    = (const float*)d_in[2];
    const float* b1    = (const float*)d_in[3];
    const float* beta2 = (const float*)d_in[4];
    const float* w2    = (const float*)d_in[5];
    const float* b2    = (const float*)d_in[6];
    float* out = (float*)d_out;

    const int* srcp = ei;
    const int* dstp = ei + N_EDGES;

    // workspace layout
    float* hA = (float*)d_ws;                          // [N,16]
    float* hB = hA + (size_t)N_NODES * HID;            // [N,16]
    float* xn = hB + (size_t)N_NODES * HID;            // [N,16]
    int* row_start = (int*)(xn + (size_t)N_NODES * HID); // [N+1]
    int* gcount    = row_start + N_NODES + 1;          // [NB]
    int* bstart    = gcount + NB;                      // [NB+1]
    int* cursor    = bstart + NB + 1;                  // [NB]
    int* binned    = cursor + NB;                      // [E] packed, then csr_src

    const int nodeGrid = (N_NODES + 255) / 256;        // 391
    const int lin1Grid = (NT + 3) / 4;                 // 1563 (4 waves/block)
    const int binGrid  = (N_EDGES + EPB - 1) / EPB;    // 782
    const int agnnGrid = N_NODES * HID / 256;          // 6250

    // ---- CSR build: coalesced two-level binning ----
    k_zero <<<1,       256, 0, stream>>>(gcount, NB);
    k_bhist<<<binGrid, 256, 0, stream>>>(dstp, gcount);
    k_bscan<<<1,       256, 0, stream>>>(gcount, bstart, cursor);
    k_bin  <<<binGrid, 256, 0, stream>>>(srcp, dstp, cursor, binned);
    k_csr  <<<NB,      512, 0, stream>>>(bstart, binned, row_start);

    // ---- network ----
    k_lin1<<<lin1Grid, 256, 0, stream>>>(x, w1, b1, hA);

    k_norm<<<nodeGrid, 256, 0, stream>>>(hA, xn);
    k_agnn<<<agnnGrid, 256, 0, stream>>>(row_start, binned, xn, hA, nullptr, hB);

    k_norm<<<nodeGrid, 256, 0, stream>>>(hB, xn);
    k_agnn<<<agnnGrid, 256, 0, stream>>>(row_start, binned, xn, hB, beta2, hA);

    k_lin2<<<nodeGrid, 256, 0, stream>>>(hA, w2, b2, out);
}